// Round 8
// baseline (26761.780 us; speedup 1.0000x reference)
//
#include <hip/hip_runtime.h>

#define HH 1024
#define TT 4096
#define NWG 256
#define NWG_PER_LAYER 128
#define JS_PER_WG 8     // 1024 / 128
#define JS_PER_WAVE 2   // 8 j's / 4 waves
#define LDS_BYTES 139264  // 128 KB w_ih tile + 8 KB h staging

__device__ __forceinline__ float fsigmoid(float x) {
    return 1.0f / (1.0f + __expf(-x));
}
__device__ __forceinline__ float ftanh(float x) {
    float ax = fabsf(x);
    float e = __expf(-2.0f * ax);
    float t = (1.0f - e) / (1.0f + e);
    return copysignf(t, x);
}
__device__ __forceinline__ void fma4(float& a, const float4 w, const float4 v) {
    a = fmaf(w.x, v.x, a);
    a = fmaf(w.y, v.y, a);
    a = fmaf(w.z, v.z, a);
    a = fmaf(w.w, v.w, a);
}
// Opaque register pin (round-6 parity).
__device__ __forceinline__ void pin4(float4& v) {
    asm volatile("" : "+v"(v.x), "+v"(v.y), "+v"(v.z), "+v"(v.w));
}
// Single agent-coherent 8B load (bypasses non-coherent L1/L2).
__device__ __forceinline__ unsigned long long ld8_llc(const void* p) {
    return __hip_atomic_load((const unsigned long long*)p,
                             __ATOMIC_RELAXED, __HIP_MEMORY_SCOPE_AGENT);
}

#define FOR_R(F) F(0) F(1) F(2) F(3) F(4) F(5) F(6) F(7)

// Persistent 2-layer LSTM, layers pipelined with skew 1.
// WGs [0,128): layer 0.  WGs [128,256): layer 1. Each wave owns 2 output rows.
//   w_ih: 128 KB LDS per WG, [wave][row][q][lane] (conflict-free ds_read_b128)
//   w_hh: compiler-managed (L2-resident scratch reload; round-7 AGPR attempt
//         regressed) -- named regs + per-iter pin, round-6 codegen.
//   h-vectors: staged ONCE per WG per step into LDS by all 256 threads
//         (round-7 lesson: per-wave uncached reads = 6 MB/step grid-wide;
//         staging cuts LLC-direct traffic 4x), same [q][lane] swizzle as w_ih.
// Grid sync: 16x16 tree barrier, monotonic epochs, all 256 WGs co-resident.
__global__ __launch_bounds__(256, 1) void lstm2_persistent(
    const float* __restrict__ x,
    const float* __restrict__ wih0, const float* __restrict__ whh0,
    const float* __restrict__ bih0, const float* __restrict__ bhh0,
    const float* __restrict__ wih1, const float* __restrict__ whh1,
    const float* __restrict__ bih1, const float* __restrict__ bhh1,
    float* __restrict__ out,     // [T][H]  h2 (output + h2 recurrence buffer)
    float* __restrict__ ring,    // [2][H]  h1 ring (layer0 <-> layer1)
    const float* __restrict__ zbuf,   // [H] zeros (h2[-1])
    unsigned* __restrict__ leaf,      // 16 counters, 128B apart (zeroed)
    unsigned* __restrict__ root)      // 1 counter (zeroed)
{
    extern __shared__ float ldsw[];   // [0,32768): w_ih  | [32768,34816): hstage

    const int wg   = blockIdx.x;
    const int tid  = threadIdx.x;
    const int wave = tid >> 6;
    const int lane = tid & 63;
    const bool isL1 = (wg >= NWG_PER_LAYER);
    const int wgl   = isL1 ? (wg - NWG_PER_LAYER) : wg;
    const int jbase = wgl * JS_PER_WG + wave * JS_PER_WAVE;
    const int col   = lane * 16;   // this lane's 16-elem chunk of the 1024-vector

    float* hstage = ldsw + 32768;  // [0,1024): inv (L1) | [1024,2048): hp

    const float* wih = isL1 ? wih1 : wih0;
    const float* whh = isL1 ? whh1 : whh0;
    const float* bih = isL1 ? bih1 : bih0;
    const float* bhh = isL1 ? bhh1 : bhh0;

    // ---- stage w_ih into LDS: float offset = wave*8192 + r*1024 + q*256 + lane*4
    #pragma unroll
    for (int r = 0; r < 8; ++r) {
        const int row = (r & 3) * HH + (jbase + (r >> 2));
        const float4* p  = (const float4*)(wih + (size_t)row * HH + col);
        float*       wb = ldsw + wave * 8192 + r * 1024 + lane * 4;
        #pragma unroll
        for (int q = 0; q < 4; ++q)
            *(float4*)(wb + q * 256) = p[q];
    }

    // ---- w_hh + bias into NAMED registers (round-6 parity) ----
    #define DECLW(r) float4 WB##r##_0, WB##r##_1, WB##r##_2, WB##r##_3; float B##r;
    FOR_R(DECLW)

    #define LOADW(r) { \
        const int row = ((r) & 3) * HH + (jbase + ((r) >> 2)); \
        const float4* ph = (const float4*)(whh + (size_t)row * HH + col); \
        WB##r##_0 = ph[0]; WB##r##_1 = ph[1]; WB##r##_2 = ph[2]; WB##r##_3 = ph[3]; \
        B##r = bih[row] + bhh[row]; }
    FOR_R(LOADW)

    #define PINW(r) pin4(WB##r##_0); pin4(WB##r##_1); pin4(WB##r##_2); pin4(WB##r##_3); \
                    asm volatile("" : "+v"(B##r));

    __syncthreads();   // LDS w_ih tile ready

    float c0v = 0.0f, c1v = 0.0f;
    int loff = wave * 8192 + lane * 4;   // this lane's LDS float offset

    // staging decomposition: thread tid loads vector elements [16L+4q, +4)
    // and writes LDS floats [256q+4L, +4)  (same swizzle as w_ih layout)
    const int sL = tid & 63, sq = tid >> 6;
    const int ge = 16 * sL + 4 * sq;   // global element offset (16B aligned)
    const int le = 256 * sq + 4 * sL;  // lds float offset (16B aligned)

    for (int k = 0; k <= TT; ++k) {
        FOR_R(PINW)
        asm volatile("" : "+v"(loff));

        const int t = isL1 ? (k - 1) : k;
        if (t >= 0 && t < TT) {
            // ---- cooperative h staging: one uncached read per vector per WG ----
            if (!isL1) {
                const float* s = ring + (size_t)((t - 1) & 1) * HH + ge;  // h1[t-1] (t=0: zeros)
                unsigned long long a = ld8_llc(s), b = ld8_llc(s + 2);
                unsigned long long* d = (unsigned long long*)(hstage + 1024 + le);
                d[0] = a; d[1] = b;
            } else {
                const float* s1 = ring + (size_t)(t & 1) * HH + ge;       // h1[t]
                unsigned long long a1 = ld8_llc(s1), b1 = ld8_llc(s1 + 2);
                const float* s2 = ((t > 0) ? out + (size_t)(t - 1) * HH : zbuf) + ge;  // h2[t-1]
                unsigned long long a2 = ld8_llc(s2), b2 = ld8_llc(s2 + 2);
                unsigned long long* d1 = (unsigned long long*)(hstage + le);
                d1[0] = a1; d1[1] = b1;
                unsigned long long* d2 = (unsigned long long*)(hstage + 1024 + le);
                d2[0] = a2; d2[1] = b2;
            }
            __syncthreads();   // staged vectors visible to all waves

            // input vector: layer0 reads x[t] (cached); layer1 from LDS stage
            float4 in4[4];
            if (!isL1) {
                const float4* p = (const float4*)(x + (size_t)t * HH + col);
                in4[0] = p[0]; in4[1] = p[1]; in4[2] = p[2]; in4[3] = p[3];
            } else {
                const float4* ip = (const float4*)(hstage + lane * 4);
                in4[0] = ip[0]; in4[1] = ip[64]; in4[2] = ip[128]; in4[3] = ip[192];
            }
            // recurrent vector from LDS stage
            float4 hp4[4];
            {
                const float4* hp = (const float4*)(hstage + 1024 + lane * 4);
                hp4[0] = hp[0]; hp4[1] = hp[64]; hp4[2] = hp[128]; hp4[3] = hp[192];
            }

            float acc0, acc1, acc2, acc3, acc4, acc5, acc6, acc7;
            #define DOTW(r) { float a = 0.0f; \
                const float4* wp = (const float4*)(ldsw + loff + (r) * 1024); \
                fma4(a, wp[0],   in4[0]); fma4(a, wp[64],  in4[1]); \
                fma4(a, wp[128], in4[2]); fma4(a, wp[192], in4[3]); \
                fma4(a, WB##r##_0, hp4[0]); fma4(a, WB##r##_1, hp4[1]); \
                fma4(a, WB##r##_2, hp4[2]); fma4(a, WB##r##_3, hp4[3]); \
                acc##r = a; }
            FOR_R(DOTW)

            // butterfly reduce all 8 accumulators across 64 lanes
            #define REDW(m) \
                acc0 += __shfl_xor(acc0, m, 64); acc1 += __shfl_xor(acc1, m, 64); \
                acc2 += __shfl_xor(acc2, m, 64); acc3 += __shfl_xor(acc3, m, 64); \
                acc4 += __shfl_xor(acc4, m, 64); acc5 += __shfl_xor(acc5, m, 64); \
                acc6 += __shfl_xor(acc6, m, 64); acc7 += __shfl_xor(acc7, m, 64);
            REDW(1) REDW(2) REDW(4) REDW(8) REDW(16) REDW(32)

            // gates (PyTorch order i,f,g,o)
            const float gi0 = fsigmoid(acc0 + B0), gf0 = fsigmoid(acc1 + B1);
            const float gg0 = ftanh(acc2 + B2),    go0 = fsigmoid(acc3 + B3);
            c0v = gf0 * c0v + gi0 * gg0;
            const float h0 = go0 * ftanh(c0v);
            const float gi1 = fsigmoid(acc4 + B4), gf1 = fsigmoid(acc5 + B5);
            const float gg1 = ftanh(acc6 + B6),    go1 = fsigmoid(acc7 + B7);
            c1v = gf1 * c1v + gi1 * gg1;
            const float h1v = go1 * ftanh(c1v);

            if (lane == 0) {
                float2 hv = make_float2(h0, h1v);   // jbase, jbase+1 (jbase even)
                unsigned long long bits;
                __builtin_memcpy(&bits, &hv, 8);
                float* dstf = isL1 ? (out  + (size_t)t * HH + jbase)
                                   : (ring + (size_t)(t & 1) * HH + jbase);
                __hip_atomic_store((unsigned long long*)dstf, bits,
                                   __ATOMIC_RELAXED, __HIP_MEMORY_SCOPE_AGENT);
            }
        }

        // ---- tree grid barrier (monotonic epochs, no L2 flushes) ----
        if (k < TT) {
            __syncthreads();   // drains all waves' stores before arrival
            if (tid == 0) {
                asm volatile("s_waitcnt vmcnt(0)" ::: "memory");  // h at LLC
                unsigned old = __hip_atomic_fetch_add(&leaf[(wg >> 4) * 32], 1u,
                                   __ATOMIC_RELAXED, __HIP_MEMORY_SCOPE_AGENT);
                if (old == (unsigned)(k * 16 + 15))   // last of 16 WGs in leaf
                    __hip_atomic_fetch_add(root, 1u,
                                   __ATOMIC_RELAXED, __HIP_MEMORY_SCOPE_AGENT);
                const unsigned tgt = (unsigned)((k + 1) * 16);
                while (__hip_atomic_load(root, __ATOMIC_RELAXED,
                                         __HIP_MEMORY_SCOPE_AGENT) < tgt)
                    __builtin_amdgcn_s_sleep(1);
            }
            __syncthreads();
        }
    }
}

extern "C" void kernel_launch(void* const* d_in, const int* in_sizes, int n_in,
                              void* d_out, int out_size, void* d_ws, size_t ws_size,
                              hipStream_t stream) {
    (void)in_sizes; (void)n_in; (void)out_size; (void)ws_size;
    const float* x    = (const float*)d_in[0];
    const float* wih0 = (const float*)d_in[1];
    const float* whh0 = (const float*)d_in[2];
    const float* bih0 = (const float*)d_in[3];
    const float* bhh0 = (const float*)d_in[4];
    const float* wih1 = (const float*)d_in[5];
    const float* whh1 = (const float*)d_in[6];
    const float* bih1 = (const float*)d_in[7];
    const float* bhh1 = (const float*)d_in[8];
    float* out = (float*)d_out;

    // ws layout: [0,2048) leaf counters (16 x 128B) | [2048,2176) root |
    //            [4096,8192) zbuf | [8192,16384) ring
    unsigned* leaf = (unsigned*)d_ws;
    unsigned* root = (unsigned*)((char*)d_ws + 2048);
    float*    zbuf = (float*)((char*)d_ws + 4096);
    float*    ring = (float*)((char*)d_ws + 8192);

    // allow 136 KB dynamic LDS (160 KB available per CU on gfx950)
    hipFuncSetAttribute((const void*)lstm2_persistent,
                        hipFuncAttributeMaxDynamicSharedMemorySize, LDS_BYTES);

    // zero counters + zbuf + ring every call (stream-ordered, graph-capturable)
    hipMemsetAsync(d_ws, 0, 16384, stream);

    hipLaunchKernelGGL(lstm2_persistent, dim3(NWG), dim3(256), LDS_BYTES, stream,
                       x, wih0, whh0, bih0, bhh0,
                       wih1, whh1, bih1, bhh1, out, ring, zbuf, leaf, root);
}

// Round 10
// 25477.139 us; speedup vs baseline: 1.0504x; 1.0504x over previous
//
#include <hip/hip_runtime.h>

#define HH 1024
#define TT 4096
#define NWG 256
#define NWG_PER_LAYER 128
#define JS_PER_WG 8     // 1024 / 128
#define JS_PER_WAVE 2   // 8 j's / 4 waves
#define LDS_BYTES 131072  // 4 waves * 8 rows * 1024 floats * 4 B (w_hh tile)

__device__ __forceinline__ float fsigmoid(float x) {
    return 1.0f / (1.0f + __expf(-x));
}
__device__ __forceinline__ float ftanh(float x) {
    float ax = fabsf(x);
    float e = __expf(-2.0f * ax);
    float t = (1.0f - e) / (1.0f + e);
    return copysignf(t, x);
}
__device__ __forceinline__ void fma4(float& a, const float4 w, const float4 v) {
    a = fmaf(w.x, v.x, a);
    a = fmaf(w.y, v.y, a);
    a = fmaf(w.z, v.z, a);
    a = fmaf(w.w, v.w, a);
}
// LLC-direct (agent-coherent) 16-float load: relaxed atomic 8B loads bypass the
// (non-coherent, possibly stale) L1/L2 and read the coherence point directly.
__device__ __forceinline__ void load16_llc(float4 v[4], const float* p) {
    const unsigned long long* q = (const unsigned long long*)p;
    #pragma unroll
    for (int i = 0; i < 4; ++i) {
        unsigned long long ua = __hip_atomic_load(q + 2 * i,     __ATOMIC_RELAXED, __HIP_MEMORY_SCOPE_AGENT);
        unsigned long long ub = __hip_atomic_load(q + 2 * i + 1, __ATOMIC_RELAXED, __HIP_MEMORY_SCOPE_AGENT);
        float2 a, b;
        __builtin_memcpy(&a, &ua, 8);
        __builtin_memcpy(&b, &ub, 8);
        v[i] = make_float4(a.x, a.y, b.x, b.y);
    }
}

#define FOR_R(F) F(0) F(1) F(2) F(3) F(4) F(5) F(6) F(7)

// Persistent 2-layer LSTM, deferred-gx schedule.
// WGs [0,128): layer 0 (processes t at step k=t).
// WGs [128,256): layer 1 (processes t at step k=t+2 -- skew 2 so the input
// GEMV can be computed one step early, off the critical chain).
// Per step: CRITICAL {load h_prev -> w_hh GEMV (LDS) -> reduce -> +bias ->
// gates -> store h} -> sync -> ARRIVE -> SLACK {gx[t+1] = w_ih @ input[t+1],
// streamed from L2, kept as per-lane partials, NO bias (round-9 bug: bias in
// per-lane partials gets multiplied 64x by the butterfly reduce)} -> sync ->
// SPIN. The slack work overlaps the barrier round-trip + stragglers.
//   w_hh: 128 KB LDS [wave][row][q][lane] (round-6-proven conflict-free b128)
//   w_ih: streamed from global (L2-resident) every step, in slack
// h-vectors exchanged through LLC via relaxed agent atomics; grid sync is a
// 16x16 tree barrier with monotonic epochs; all 256 WGs co-resident (1 WG/CU).
__global__ __launch_bounds__(256, 1) void lstm2_persistent(
    const float* __restrict__ x,
    const float* __restrict__ wih0, const float* __restrict__ whh0,
    const float* __restrict__ bih0, const float* __restrict__ bhh0,
    const float* __restrict__ wih1, const float* __restrict__ whh1,
    const float* __restrict__ bih1, const float* __restrict__ bhh1,
    float* __restrict__ out,     // [T][H]  h2 (output + h2 recurrence buffer)
    float* __restrict__ ring,    // [4][H]  h1 ring (layer0 <-> layer1)
    const float* __restrict__ zbuf,   // [H] zeros (h[-1])
    unsigned* __restrict__ leaf,      // 16 counters, 128B apart (zeroed)
    unsigned* __restrict__ root)      // 1 counter (zeroed)
{
    extern __shared__ float ldsw[];   // w_hh tile, 128 KB

    const int wg   = blockIdx.x;
    const int tid  = threadIdx.x;
    const int wave = tid >> 6;
    const int lane = tid & 63;
    const bool isL1 = (wg >= NWG_PER_LAYER);
    const int wgl   = isL1 ? (wg - NWG_PER_LAYER) : wg;
    const int jbase = wgl * JS_PER_WG + wave * JS_PER_WAVE;
    const int col   = lane * 16;   // this lane's 16-elem chunk of the 1024-vector

    const float* wih = isL1 ? wih1 : wih0;
    const float* whh = isL1 ? whh1 : whh0;
    const float* bih = isL1 ? bih1 : bih0;
    const float* bhh = isL1 ? bhh1 : bhh0;

    // ---- stage w_hh into LDS: float offset = wave*8192 + r*1024 + q*256 + lane*4
    #pragma unroll
    for (int r = 0; r < 8; ++r) {
        const int row = (r & 3) * HH + (jbase + (r >> 2));
        const float4* p  = (const float4*)(whh + (size_t)row * HH + col);
        float*       wb = ldsw + wave * 8192 + r * 1024 + lane * 4;
        #pragma unroll
        for (int q = 0; q < 4; ++q)
            *(float4*)(wb + q * 256) = p[q];
    }

    // ---- bias (applied AFTER the butterfly reduce, uniform across lanes) ----
    #define DECLB(r) float B##r; { const int row = ((r)&3)*HH + (jbase + ((r)>>2)); \
                                   B##r = bih[row] + bhh[row]; }
    FOR_R(DECLB)

    // gx per-lane partials, carried in registers across the step boundary
    #define DECLG(r) float gxp##r = 0.0f;
    FOR_R(DECLG)

    float c0v = 0.0f, c1v = 0.0f;
    int loff  = wave * 8192 + lane * 4;  // LDS float offset (pinned per iter)
    int wioff = 0;                       // global w_ih offset (pinned per iter)

    // streamed input-GEMV partial: gxp_r = w_ih[rows(r)][col..col+16) @ iv
    // (NO bias here -- per-lane partials get summed 64x by the reduce)
    #define GXR(r) { \
        const int row = ((r) & 3) * HH + (jbase + ((r) >> 2)); \
        const float4* wp = (const float4*)(wih + (size_t)row * HH + col + wioff); \
        float4 w0 = wp[0], w1 = wp[1], w2 = wp[2], w3 = wp[3]; \
        float a = 0.0f; \
        fma4(a, w0, iv4[0]); fma4(a, w1, iv4[1]); \
        fma4(a, w2, iv4[2]); fma4(a, w3, iv4[3]); \
        gxp##r = a; }

    // ---- prologue: L0 needs gx[0] before the first step ----
    if (!isL1) {
        float4 iv4[4];
        const float4* p = (const float4*)(x + col);
        iv4[0] = p[0]; iv4[1] = p[1]; iv4[2] = p[2]; iv4[3] = p[3];
        FOR_R(GXR)
    }

    __syncthreads();   // LDS w_hh tile ready

    for (int k = 0; k <= TT + 1; ++k) {
        // per-iteration pins: block LICM of the (address-invariant) LDS w_hh
        // reads and global w_ih loads into spillable long-lived registers
        asm volatile("" : "+v"(loff), "+v"(wioff));

        const int t = isL1 ? (k - 2) : k;

        // ================= CRITICAL phase =================
        if (t >= 0 && t < TT) {
            float4 hp4[4];
            const float* hpv = (t > 0)
                ? (isL1 ? out + (size_t)(t - 1) * HH : ring + (size_t)((t - 1) & 3) * HH)
                : zbuf;
            load16_llc(hp4, hpv + col);

            float acc0, acc1, acc2, acc3, acc4, acc5, acc6, acc7;
            #define DOTW(r) { float a = gxp##r; \
                const float4* wp = (const float4*)(ldsw + loff + (r) * 1024); \
                fma4(a, wp[0],   hp4[0]); fma4(a, wp[64],  hp4[1]); \
                fma4(a, wp[128], hp4[2]); fma4(a, wp[192], hp4[3]); \
                acc##r = a; }
            FOR_R(DOTW)

            #define REDW(m) \
                acc0 += __shfl_xor(acc0, m, 64); acc1 += __shfl_xor(acc1, m, 64); \
                acc2 += __shfl_xor(acc2, m, 64); acc3 += __shfl_xor(acc3, m, 64); \
                acc4 += __shfl_xor(acc4, m, 64); acc5 += __shfl_xor(acc5, m, 64); \
                acc6 += __shfl_xor(acc6, m, 64); acc7 += __shfl_xor(acc7, m, 64);
            REDW(1) REDW(2) REDW(4) REDW(8) REDW(16) REDW(32)

            // gates (PyTorch order i,f,g,o); bias added post-reduce
            const float gi0 = fsigmoid(acc0 + B0), gf0 = fsigmoid(acc1 + B1);
            const float gg0 = ftanh(acc2 + B2),    go0 = fsigmoid(acc3 + B3);
            c0v = gf0 * c0v + gi0 * gg0;
            const float h0 = go0 * ftanh(c0v);
            const float gi1 = fsigmoid(acc4 + B4), gf1 = fsigmoid(acc5 + B5);
            const float gg1 = ftanh(acc6 + B6),    go1 = fsigmoid(acc7 + B7);
            c1v = gf1 * c1v + gi1 * gg1;
            const float h1v = go1 * ftanh(c1v);

            if (lane == 0) {
                float2 hv = make_float2(h0, h1v);   // jbase, jbase+1 (jbase even)
                unsigned long long bits;
                __builtin_memcpy(&bits, &hv, 8);
                float* dstf = isL1 ? (out  + (size_t)t * HH + jbase)
                                   : (ring + (size_t)(t & 3) * HH + jbase);
                __hip_atomic_store((unsigned long long*)dstf, bits,
                                   __ATOMIC_RELAXED, __HIP_MEMORY_SCOPE_AGENT);
            }
        }

        __syncthreads();   // all 4 waves' h stores drained (vmcnt before s_barrier)

        // ================= ARRIVE (no spin yet) =================
        if (tid == 0 && k <= TT) {
            asm volatile("s_waitcnt vmcnt(0)" ::: "memory");
            unsigned old = __hip_atomic_fetch_add(&leaf[(wg >> 4) * 32], 1u,
                               __ATOMIC_RELAXED, __HIP_MEMORY_SCOPE_AGENT);
            if (old == (unsigned)(k * 16 + 15))   // last of 16 WGs in leaf
                __hip_atomic_fetch_add(root, 1u,
                               __ATOMIC_RELAXED, __HIP_MEMORY_SCOPE_AGENT);
        }

        // ================= SLACK phase (overlaps barrier) =================
        // compute gx for this layer's next timestep; inputs were made visible
        // by the PREVIOUS barrier, so this needs no synchronization.
        {
            const int tn = t + 1;
            if (tn >= 0 && tn < TT) {
                float4 iv4[4];
                if (!isL1) {
                    const float4* p = (const float4*)(x + (size_t)tn * HH + col);
                    iv4[0] = p[0]; iv4[1] = p[1]; iv4[2] = p[2]; iv4[3] = p[3];
                } else {
                    load16_llc(iv4, ring + (size_t)(tn & 3) * HH + col);
                }
                FOR_R(GXR)
            }
        }
        // anchor gx results here so the slack work cannot sink past the spin
        asm volatile("" : "+v"(gxp0), "+v"(gxp1), "+v"(gxp2), "+v"(gxp3),
                         "+v"(gxp4), "+v"(gxp5), "+v"(gxp6), "+v"(gxp7));

        // ================= SPIN =================
        if (k <= TT) {
            __syncthreads();
            if (tid == 0) {
                const unsigned tgt = (unsigned)((k + 1) * 16);
                while (__hip_atomic_load(root, __ATOMIC_RELAXED,
                                         __HIP_MEMORY_SCOPE_AGENT) < tgt)
                    __builtin_amdgcn_s_sleep(1);
            }
            __syncthreads();
        }
    }
}

extern "C" void kernel_launch(void* const* d_in, const int* in_sizes, int n_in,
                              void* d_out, int out_size, void* d_ws, size_t ws_size,
                              hipStream_t stream) {
    (void)in_sizes; (void)n_in; (void)out_size; (void)ws_size;
    const float* x    = (const float*)d_in[0];
    const float* wih0 = (const float*)d_in[1];
    const float* whh0 = (const float*)d_in[2];
    const float* bih0 = (const float*)d_in[3];
    const float* bhh0 = (const float*)d_in[4];
    const float* wih1 = (const float*)d_in[5];
    const float* whh1 = (const float*)d_in[6];
    const float* bih1 = (const float*)d_in[7];
    const float* bhh1 = (const float*)d_in[8];
    float* out = (float*)d_out;

    // ws layout: [0,2048) leaf counters (16 x 128B) | [2048,2176) root |
    //            [4096,8192) zbuf | [8192,24576) ring (4 slots x 4 KB)
    unsigned* leaf = (unsigned*)d_ws;
    unsigned* root = (unsigned*)((char*)d_ws + 2048);
    float*    zbuf = (float*)((char*)d_ws + 4096);
    float*    ring = (float*)((char*)d_ws + 8192);

    // allow 128 KB dynamic LDS (160 KB available per CU on gfx950)
    hipFuncSetAttribute((const void*)lstm2_persistent,
                        hipFuncAttributeMaxDynamicSharedMemorySize, LDS_BYTES);

    // zero counters + zbuf + ring every call (stream-ordered, graph-capturable)
    hipMemsetAsync(d_ws, 0, 24576, stream);

    hipLaunchKernelGGL(lstm2_persistent, dim3(NWG), dim3(256), LDS_BYTES, stream,
                       x, wih0, whh0, bih0, bhh0,
                       wih1, whh1, bih1, bhh1, out, ring, zbuf, leaf, root);
}

// Round 11
// 20103.418 us; speedup vs baseline: 1.3312x; 1.2673x over previous
//
#include <hip/hip_runtime.h>

#define HH 1024
#define TT 4096
#define NWG 256
#define NWG_PER_LAYER 128
#define JS_PER_WG 8     // 1024 / 128
#define JS_PER_WAVE 2   // 8 j's / 4 waves
#define LDS_BYTES 131072  // 4 waves * 8 rows * 1024 floats * 4 B (w_hh tile)

__device__ __forceinline__ float fsigmoid(float x) {
    return 1.0f / (1.0f + __expf(-x));
}
__device__ __forceinline__ float ftanh(float x) {
    float ax = fabsf(x);
    float e = __expf(-2.0f * ax);
    float t = (1.0f - e) / (1.0f + e);
    return copysignf(t, x);
}
__device__ __forceinline__ void fma4(float& a, const float4 w, const float4 v) {
    a = fmaf(w.x, v.x, a);
    a = fmaf(w.y, v.y, a);
    a = fmaf(w.z, v.z, a);
    a = fmaf(w.w, v.w, a);
}

// LLC-coherent 64B load, ONE round-trip: 4 pipelined global_load_dwordx4 with
// sc0 sc1 (bypass non-coherent L1/L2, read at the coherence point) and a
// single vmcnt(0). Round-10 lesson: 8 separate __hip_atomic_loads serialize
// into 8 LLC round-trips (~3 us) -- the hidden dominant term of every round
// since r4.
__device__ __forceinline__ void load64B_llc(float4 v[4], const float* p) {
    asm volatile(
        "global_load_dwordx4 %0, %4, off sc0 sc1\n\t"
        "global_load_dwordx4 %1, %4, off offset:16 sc0 sc1\n\t"
        "global_load_dwordx4 %2, %4, off offset:32 sc0 sc1\n\t"
        "global_load_dwordx4 %3, %4, off offset:48 sc0 sc1\n\t"
        "s_waitcnt vmcnt(0)"
        : "=&v"(v[0]), "=&v"(v[1]), "=&v"(v[2]), "=&v"(v[3])
        : "v"(p)
        : "memory");
}

#define FOR_R(F) F(0) F(1) F(2) F(3) F(4) F(5) F(6) F(7)

// Persistent 2-layer LSTM, deferred-gx schedule (round-10 structure).
// WGs [0,128): layer 0 (t = k). WGs [128,256): layer 1 (t = k-2, skew 2).
// Per step: CRITICAL {1-RT h load -> w_hh GEMV (LDS) -> reduce -> +bias ->
// gates -> store h} -> sync -> ARRIVE -> SLACK {gx[t+1] = w_ih @ input[t+1],
// streamed from L2, per-lane partials, no bias} -> sync -> SPIN.
//   w_hh: 128 KB LDS [wave][row][q][lane] (conflict-free ds_read_b128)
//   w_ih: streamed from global (L2-resident) every step, in slack
// h-vectors: LLC via sc0/sc1 loads + relaxed agent atomic stores. Grid sync:
// 16x16 tree barrier, monotonic epochs, all 256 WGs co-resident (1 WG/CU).
__global__ __launch_bounds__(256, 1) void lstm2_persistent(
    const float* __restrict__ x,
    const float* __restrict__ wih0, const float* __restrict__ whh0,
    const float* __restrict__ bih0, const float* __restrict__ bhh0,
    const float* __restrict__ wih1, const float* __restrict__ whh1,
    const float* __restrict__ bih1, const float* __restrict__ bhh1,
    float* __restrict__ out,     // [T][H]  h2 (output + h2 recurrence buffer)
    float* __restrict__ ring,    // [4][H]  h1 ring (layer0 <-> layer1)
    const float* __restrict__ zbuf,   // [H] zeros (h[-1])
    unsigned* __restrict__ leaf,      // 16 counters, 128B apart (zeroed)
    unsigned* __restrict__ root)      // 1 counter (zeroed)
{
    extern __shared__ float ldsw[];   // w_hh tile, 128 KB

    const int wg   = blockIdx.x;
    const int tid  = threadIdx.x;
    const int wave = tid >> 6;
    const int lane = tid & 63;
    const bool isL1 = (wg >= NWG_PER_LAYER);
    const int wgl   = isL1 ? (wg - NWG_PER_LAYER) : wg;
    const int jbase = wgl * JS_PER_WG + wave * JS_PER_WAVE;
    const int col   = lane * 16;   // this lane's 16-elem chunk of the 1024-vector

    const float* wih = isL1 ? wih1 : wih0;
    const float* whh = isL1 ? whh1 : whh0;
    const float* bih = isL1 ? bih1 : bih0;
    const float* bhh = isL1 ? bhh1 : bhh0;

    // ---- stage w_hh into LDS: float offset = wave*8192 + r*1024 + q*256 + lane*4
    #pragma unroll
    for (int r = 0; r < 8; ++r) {
        const int row = (r & 3) * HH + (jbase + (r >> 2));
        const float4* p  = (const float4*)(whh + (size_t)row * HH + col);
        float*       wb = ldsw + wave * 8192 + r * 1024 + lane * 4;
        #pragma unroll
        for (int q = 0; q < 4; ++q)
            *(float4*)(wb + q * 256) = p[q];
    }

    // ---- bias (applied AFTER the butterfly reduce, uniform across lanes) ----
    #define DECLB(r) float B##r; { const int row = ((r)&3)*HH + (jbase + ((r)>>2)); \
                                   B##r = bih[row] + bhh[row]; }
    FOR_R(DECLB)

    // gx per-lane partials, carried in registers across the step boundary
    #define DECLG(r) float gxp##r = 0.0f;
    FOR_R(DECLG)

    float c0v = 0.0f, c1v = 0.0f;
    int loff  = wave * 8192 + lane * 4;  // LDS float offset (pinned per iter)
    int wioff = 0;                       // global w_ih offset (pinned per iter)

    // streamed input-GEMV partial: gxp_r = w_ih[rows(r)][col..col+16) @ iv
    // (NO bias here -- per-lane partials get summed 64x by the reduce)
    #define GXR(r) { \
        const int row = ((r) & 3) * HH + (jbase + ((r) >> 2)); \
        const float4* wp = (const float4*)(wih + (size_t)row * HH + col + wioff); \
        float4 w0 = wp[0], w1 = wp[1], w2 = wp[2], w3 = wp[3]; \
        float a = 0.0f; \
        fma4(a, w0, iv4[0]); fma4(a, w1, iv4[1]); \
        fma4(a, w2, iv4[2]); fma4(a, w3, iv4[3]); \
        gxp##r = a; }

    // ---- prologue: L0 needs gx[0] before the first step ----
    if (!isL1) {
        float4 iv4[4];
        const float4* p = (const float4*)(x + col);
        iv4[0] = p[0]; iv4[1] = p[1]; iv4[2] = p[2]; iv4[3] = p[3];
        FOR_R(GXR)
    }

    __syncthreads();   // LDS w_hh tile ready

    for (int k = 0; k <= TT + 1; ++k) {
        // per-iteration pins: block LICM of the (address-invariant) LDS w_hh
        // reads and global w_ih loads into spillable long-lived registers
        asm volatile("" : "+v"(loff), "+v"(wioff));

        const int t = isL1 ? (k - 2) : k;

        // ================= CRITICAL phase =================
        if (t >= 0 && t < TT) {
            float4 hp4[4];
            const float* hpv = (t > 0)
                ? (isL1 ? out + (size_t)(t - 1) * HH : ring + (size_t)((t - 1) & 3) * HH)
                : zbuf;
            load64B_llc(hp4, hpv + col);

            float acc0, acc1, acc2, acc3, acc4, acc5, acc6, acc7;
            #define DOTW(r) { float a = gxp##r; \
                const float4* wp = (const float4*)(ldsw + loff + (r) * 1024); \
                fma4(a, wp[0],   hp4[0]); fma4(a, wp[64],  hp4[1]); \
                fma4(a, wp[128], hp4[2]); fma4(a, wp[192], hp4[3]); \
                acc##r = a; }
            FOR_R(DOTW)

            #define REDW(m) \
                acc0 += __shfl_xor(acc0, m, 64); acc1 += __shfl_xor(acc1, m, 64); \
                acc2 += __shfl_xor(acc2, m, 64); acc3 += __shfl_xor(acc3, m, 64); \
                acc4 += __shfl_xor(acc4, m, 64); acc5 += __shfl_xor(acc5, m, 64); \
                acc6 += __shfl_xor(acc6, m, 64); acc7 += __shfl_xor(acc7, m, 64);
            REDW(1) REDW(2) REDW(4) REDW(8) REDW(16) REDW(32)

            // gates (PyTorch order i,f,g,o); bias added post-reduce
            const float gi0 = fsigmoid(acc0 + B0), gf0 = fsigmoid(acc1 + B1);
            const float gg0 = ftanh(acc2 + B2),    go0 = fsigmoid(acc3 + B3);
            c0v = gf0 * c0v + gi0 * gg0;
            const float h0 = go0 * ftanh(c0v);
            const float gi1 = fsigmoid(acc4 + B4), gf1 = fsigmoid(acc5 + B5);
            const float gg1 = ftanh(acc6 + B6),    go1 = fsigmoid(acc7 + B7);
            c1v = gf1 * c1v + gi1 * gg1;
            const float h1v = go1 * ftanh(c1v);

            if (lane == 0) {
                float2 hv = make_float2(h0, h1v);   // jbase, jbase+1 (jbase even)
                unsigned long long bits;
                __builtin_memcpy(&bits, &hv, 8);
                float* dstf = isL1 ? (out  + (size_t)t * HH + jbase)
                                   : (ring + (size_t)(t & 3) * HH + jbase);
                __hip_atomic_store((unsigned long long*)dstf, bits,
                                   __ATOMIC_RELAXED, __HIP_MEMORY_SCOPE_AGENT);
            }
        }

        __syncthreads();   // all 4 waves' h stores drained (vmcnt before s_barrier)

        // ================= ARRIVE (no spin yet) =================
        if (tid == 0 && k <= TT) {
            asm volatile("s_waitcnt vmcnt(0)" ::: "memory");
            unsigned old = __hip_atomic_fetch_add(&leaf[(wg >> 4) * 32], 1u,
                               __ATOMIC_RELAXED, __HIP_MEMORY_SCOPE_AGENT);
            if (old == (unsigned)(k * 16 + 15))   // last of 16 WGs in leaf
                __hip_atomic_fetch_add(root, 1u,
                               __ATOMIC_RELAXED, __HIP_MEMORY_SCOPE_AGENT);
        }

        // ================= SLACK phase (overlaps barrier) =================
        // compute gx for this layer's next timestep; inputs were made visible
        // by the PREVIOUS barrier, so this needs no synchronization.
        {
            const int tn = t + 1;
            if (tn >= 0 && tn < TT) {
                float4 iv4[4];
                if (!isL1) {
                    const float4* p = (const float4*)(x + (size_t)tn * HH + col);
                    iv4[0] = p[0]; iv4[1] = p[1]; iv4[2] = p[2]; iv4[3] = p[3];
                } else {
                    load64B_llc(iv4, ring + (size_t)(tn & 3) * HH + col);
                }
                FOR_R(GXR)
            }
        }
        // anchor gx results here so the slack work cannot sink past the spin
        asm volatile("" : "+v"(gxp0), "+v"(gxp1), "+v"(gxp2), "+v"(gxp3),
                         "+v"(gxp4), "+v"(gxp5), "+v"(gxp6), "+v"(gxp7));

        // ================= SPIN =================
        if (k <= TT) {
            __syncthreads();
            if (tid == 0) {
                const unsigned tgt = (unsigned)((k + 1) * 16);
                while (__hip_atomic_load(root, __ATOMIC_RELAXED,
                                         __HIP_MEMORY_SCOPE_AGENT) < tgt)
                    __builtin_amdgcn_s_sleep(1);
            }
            __syncthreads();
        }
    }
}

extern "C" void kernel_launch(void* const* d_in, const int* in_sizes, int n_in,
                              void* d_out, int out_size, void* d_ws, size_t ws_size,
                              hipStream_t stream) {
    (void)in_sizes; (void)n_in; (void)out_size; (void)ws_size;
    const float* x    = (const float*)d_in[0];
    const float* wih0 = (const float*)d_in[1];
    const float* whh0 = (const float*)d_in[2];
    const float* bih0 = (const float*)d_in[3];
    const float* bhh0 = (const float*)d_in[4];
    const float* wih1 = (const float*)d_in[5];
    const float* whh1 = (const float*)d_in[6];
    const float* bih1 = (const float*)d_in[7];
    const float* bhh1 = (const float*)d_in[8];
    float* out = (float*)d_out;

    // ws layout: [0,2048) leaf counters (16 x 128B) | [2048,2176) root |
    //            [4096,8192) zbuf | [8192,24576) ring (4 slots x 4 KB)
    unsigned* leaf = (unsigned*)d_ws;
    unsigned* root = (unsigned*)((char*)d_ws + 2048);
    float*    zbuf = (float*)((char*)d_ws + 4096);
    float*    ring = (float*)((char*)d_ws + 8192);

    // allow 128 KB dynamic LDS (160 KB available per CU on gfx950)
    hipFuncSetAttribute((const void*)lstm2_persistent,
                        hipFuncAttributeMaxDynamicSharedMemorySize, LDS_BYTES);

    // zero counters + zbuf + ring every call (stream-ordered, graph-capturable)
    hipMemsetAsync(d_ws, 0, 24576, stream);

    hipLaunchKernelGGL(lstm2_persistent, dim3(NWG), dim3(256), LDS_BYTES, stream,
                       x, wih0, whh0, bih0, bhh0,
                       wih1, whh1, bih1, bhh1, out, ring, zbuf, leaf, root);
}